// Round 11
// baseline (997.024 us; speedup 1.0000x reference)
//
#include <hip/hip_runtime.h>
#include <hip/hip_bf16.h>

#define BSZ 8
#define PAIRS 5
#define NCH 2
#define HWP 128
#define PP 64
#define DIM 512
#define NHEAD 8
#define DHEAD 64
#define DFF 2048
#define NLAYER 6
#define SEQ 640
#define NTOK (BSZ * SEQ)   // 5120
#define FIN 10
#define MPOST (BSZ * PAIRS * PP)   // 2560

typedef unsigned short u16;
typedef __bf16 bf16_t;
typedef __attribute__((ext_vector_type(8))) __bf16 bf16x8;
typedef __attribute__((ext_vector_type(8))) unsigned short u16x8;
typedef __attribute__((ext_vector_type(4))) unsigned short u16x4;
typedef __attribute__((ext_vector_type(4))) float f32x4;
#define MFMA16(a, b, c) __builtin_amdgcn_mfma_f32_16x16x32_bf16(a, b, c, 0, 0, 0)

__device__ __forceinline__ u16 f2b(float x) {   // RNE f32->bf16
  unsigned u = __float_as_uint(x);
  return (u16)((u + 0x7fffu + ((u >> 16) & 1u)) >> 16);
}

// tanh-form GELU (error vs exact erf-GELU <~1e-3; margin is 0.032)
__device__ __forceinline__ float gelu_t(float x) {
  float y = 0.7978845608f * (x + 0.044715f * x * x * x);
  y = fminf(fmaxf(y, -10.f), 10.f);
  float e = __expf(2.f * y);
  return 0.5f * x * (1.f + (e - 1.f) / (e + 1.f));
}

// async global->LDS DMA, 16B/lane; LDS dest = wave-uniform base + lane*16
__device__ __forceinline__ void dma16(const u16* g, void* l) {
  __builtin_amdgcn_global_load_lds(
      (const __attribute__((address_space(1))) void*)g,
      (__attribute__((address_space(3))) void*)l, 16, 0, 0);
}

template <int N> __device__ __forceinline__ void vwait() {
  if constexpr (N == 0) asm volatile("s_waitcnt vmcnt(0)" ::: "memory");
  else if constexpr (N == 4) asm volatile("s_waitcnt vmcnt(4)" ::: "memory");
  else if constexpr (N == 8) asm volatile("s_waitcnt vmcnt(8)" ::: "memory");
}

#define W_QKV (3 * DIM * DIM)   // 786432
#define W_O (DIM * DIM)         // 262144
#define W_1 (DFF * DIM)         // 1048576
#define OFF_O W_QKV
#define OFF_1 (W_QKV + W_O)
#define OFF_2 (W_QKV + W_O + W_1)
#define W_ALL (W_QKV + W_O + 2 * W_1)   // 3145728
#define PREPOST (2 * DIM * DIM)         // 524288
#define N_CVT (PREPOST + NLAYER * W_ALL)   // 19398656

// ---------------- ALL weights f32->bf16, 8 elems/thread, 16B stores
__global__ __launch_bounds__(256) void k_cvt_all(const float* __restrict__ preW,
                                                 const float* __restrict__ postW,
                                                 const float* __restrict__ wq,
                                                 const float* __restrict__ wo,
                                                 const float* __restrict__ w1,
                                                 const float* __restrict__ w2,
                                                 u16* __restrict__ dst) {
  size_t i = ((size_t)blockIdx.x * 256 + threadIdx.x) * 8;   // < N_CVT
  const float* src;
  size_t off;
  if (i < DIM * DIM) { src = preW; off = i; }
  else if (i < PREPOST) { src = postW; off = i - DIM * DIM; }
  else {
    size_t j = i - PREPOST;
    int l = (int)(j / W_ALL);
    size_t r = j - (size_t)l * W_ALL;
    if (r < OFF_O) { src = wq + (size_t)l * W_QKV; off = r; }
    else if (r < OFF_1) { src = wo + (size_t)l * W_O; off = r - OFF_O; }
    else if (r < OFF_2) { src = w1 + (size_t)l * W_1; off = r - OFF_1; }
    else { src = w2 + (size_t)l * W_1; off = r - OFF_2; }
  }
  float4 v0 = *(const float4*)(src + off);
  float4 v1 = *(const float4*)(src + off + 4);
  u16x8 o;
  o[0] = f2b(v0.x); o[1] = f2b(v0.y); o[2] = f2b(v0.z); o[3] = f2b(v0.w);
  o[4] = f2b(v1.x); o[5] = f2b(v1.y); o[6] = f2b(v1.z); o[7] = f2b(v1.w);
  *(u16x8*)(dst + i) = o;
}

// ---------------- patchify -> bf16 A[NTOK][512]
__global__ __launch_bounds__(256) void k_patchify(const float* __restrict__ init,
                                                  const float* __restrict__ endp,
                                                  u16* __restrict__ A) {
  int i = blockIdx.x * 256 + threadIdx.x;
  int d = i & 511;
  int g = i >> 9;
  int p = g & 63;
  int fi = (g >> 6) % FIN;
  int b = g / SEQ;
  int e = fi & 1;
  int pr = fi >> 1;
  int c = d >> 8;
  int r1 = (d >> 4) & 15;
  int r2 = d & 15;
  int row = ((p >> 3) << 4) + r1;
  int col = ((p & 7) << 4) + r2;
  const float* src = e ? endp : init;
  size_t off = ((size_t)((b * PAIRS + pr) * NCH + c) << 14) + (size_t)row * HWP + col;
  A[i] = f2b(src[off]);
}

// ---------------- bf16 MFMA GEMM, ZERO-BARRIER (R11): per-wave PRIVATE
// staging. Each wave DMAs exactly the A-half (32x32) and B-half (32x32) it
// consumes into its own LDS region -> no cross-wave LDS sharing -> no
// s_barrier anywhere; each wave self-paces on its own vmcnt. 8 independent
// wave-chains/CU (2 blocks x 4 waves) overlap the staging latency that
// barrier-coupled blocks could not (R4->R10 mechanism at full strength).
// Safety (single-wave program order): ds_reads of round it-2 lgkm-complete
// before round-it DMA to that buffer is issued; round it+2 reads sit behind
// the explicit vmcnt(8). Staging bytes x2 (each chunk loaded by 2 waves) —
// L2 has >=5x headroom. 4-buffer, BK=32, stage-ahead-2, vmcnt(8/4/0).
// BY-MAJOR XCD swizzle (R5). Fixed 64x64 tile, 4 waves 2x2, LDS 64KB.
// MODE 0: outB = act(A·B^T + bias) bf16
// MODE 1: outP = raw f32 partial
// MODE 2: pre epilogue: +bias+patch_pos+func_pos -> outF f32 + outB bf16
// MODE 3: post epilogue: +bias, depatchify scatter -> outF (A compact rows)
// GATHER: A rows are init-slot tokens of a full-layout buffer
template <int MODE, int GATHER>
__global__ __launch_bounds__(256) void k_mma(const u16* __restrict__ A,
                                             const u16* __restrict__ B,
                                             const float* __restrict__ bias,
                                             u16* __restrict__ outB,
                                             float* __restrict__ outP,
                                             float* __restrict__ outF,
                                             const float* __restrict__ pp,
                                             const float* __restrict__ fp,
                                             int M, int N, int K, int act) {
  // S[buf][wave][chunk][16][32]: chunks 0,1 = wave's A rows; 2,3 = B rows
  __shared__ __align__(16) bf16_t S[4][4][4][16][32];
  const int t = threadIdx.x;
  const int w = t >> 6, lane = t & 63, quad = lane >> 4, l16 = lane & 15;
  int bx = blockIdx.x, by = blockIdx.y;
  if ((gridDim.y & 7) == 0) {       // by-major XCD swizzle (A-row locality)
    int lin = bx + gridDim.x * by;
    int xcd = lin & 7, slot = lin >> 3;
    int gx = gridDim.x;
    by = (gridDim.y >> 3) * xcd + slot / gx;
    bx = slot % gx;
  }
  const int row0 = by * 64, col0 = bx * 64;
  const int mB = (w & 1) * 32;
  const int nB = (w >> 1) * 32;

  // per-lane source pointers for this wave's own chunks
  const u16* aP[2];
#pragma unroll
  for (int c = 0; c < 2; ++c) {
    int r = row0 + mB + c * 16 + (lane >> 2);
    int g = r;
    if (GATHER) {
      int p = r & 63, pr = (r >> 6) % PAIRS, b = r / (PAIRS * PP);
      g = b * SEQ + pr * 128 + p;
    }
    aP[c] = A + (size_t)g * K + ((lane & 3) << 3);
  }
  const u16* bP = B + (size_t)(col0 + nB + (lane >> 2)) * K + ((lane & 3) << 3);

  f32x4 acc[2][2];
#pragma unroll
  for (int i = 0; i < 2; ++i)
#pragma unroll
    for (int j = 0; j < 2; ++j) acc[i][j] = (f32x4){0.f, 0.f, 0.f, 0.f};

  auto stage = [&](int bu, int kk) {
    dma16(aP[0] + kk, &S[bu][w][0][0][0]);
    dma16(aP[1] + kk, &S[bu][w][1][0][0]);
    dma16(bP + kk, &S[bu][w][2][0][0]);
    dma16(bP + (size_t)16 * K + kk, &S[bu][w][3][0][0]);
  };

  const int iters = K >> 5;
  stage(0, 0);
  stage(1, 32);
  for (int it = 0; it < iters; ++it) {
    const int cur = it & 3;
    if (it + 2 < iters) stage((it + 2) & 3, (it + 2) << 5);  // stays in flight
    if (it + 2 < iters) vwait<8>();       // wait only tile `it` (own 4 DMAs)
    else if (it + 1 < iters) vwait<4>();
    else vwait<0>();
    // no barrier: all staged data is wave-private
    bf16x8 af[2], bfr[2];
#pragma unroll
    for (int i = 0; i < 2; ++i)
      af[i] = *(const bf16x8*)&S[cur][w][i][l16][quad * 8];
#pragma unroll
    for (int j = 0; j < 2; ++j)
      bfr[j] = *(const bf16x8*)&S[cur][w][2 + j][l16][quad * 8];
#pragma unroll
    for (int i = 0; i < 2; ++i)
#pragma unroll
      for (int j = 0; j < 2; ++j) acc[i][j] = MFMA16(af[i], bfr[j], acc[i][j]);
  }

#pragma unroll
  for (int i = 0; i < 2; ++i)
#pragma unroll
    for (int reg = 0; reg < 4; ++reg) {
      int m = row0 + mB + i * 16 + quad * 4 + reg;
#pragma unroll
      for (int j = 0; j < 2; ++j) {
        int n = col0 + nB + j * 16 + l16;
        float v = acc[i][j][reg];
        if (MODE == 0) {
          v += bias[n];
          if (act) v = gelu_t(v);
          outB[(size_t)m * N + n] = f2b(v);
        } else if (MODE == 1) {
          outP[(size_t)m * N + n] = v;
        } else if (MODE == 2) {
          int p = m & 63, fi = (m >> 6) % FIN;
          v += bias[n] + pp[p * DIM + n] + fp[fi * DIM + n];
          outF[(size_t)m * N + n] = v;
          outB[(size_t)m * N + n] = f2b(v);
        } else {   // MODE 3: depatchify scatter (A/m compact init rows)
          v += bias[n];
          int p = m & 63, pr = (m >> 6) % PAIRS, b = m / (PAIRS * PP);
          int c = n >> 8, r1 = (n >> 4) & 15, r2 = n & 15;
          int row = ((p >> 3) << 4) + r1, col = ((p & 7) << 4) + r2;
          size_t off = ((size_t)((b * PAIRS + pr) * NCH + c) << 14) +
                       (size_t)row * HWP + col;
          outF[off] = v;
        }
      }
    }
}

// ---------------- fused flash attention (bf16 MFMA), ONE barrier per K-tile.
// R10 barrier audit: Ps and Qs are WAVE-LOCAL (rows [16w,16w+16) written and
// read by wave w only) -> softmax->PV sync and Q-stage sync unnecessary.
// K/V double-buffered: store tile kt+1 into parity buffer cur^1 (R4-style
// safety). LPT dispatch (R9): qblk reversed so heaviest blocks launch first.
// qmul: q-block stride (layer 5 only needs even q-blocks -> qmul=2)
__global__ __launch_bounds__(256) void k_attn(const u16* __restrict__ qkv,
                                              u16* __restrict__ o, int qmul) {
  __shared__ bf16_t Ks[2][64][72];
  __shared__ bf16_t Vs[2][64][72];   // transposed: Vs[.][d][tok]
  __shared__ bf16_t QPs[64][72];     // Q staging, then P transpose (wave-local)
  const int t = threadIdx.x;
  const int w = t >> 6, lane = t & 63, quad = lane >> 4, l16 = lane & 15;
  const int qblk = ((int)gridDim.x - 1 - (int)blockIdx.x) * qmul;  // LPT order
  const int h = blockIdx.y, b = blockIdx.z;
  const int q0 = qblk << 6;
  const u16* base = qkv + (size_t)b * SEQ * (3 * DIM);
  const int sr = t >> 2;
  const int sd = (t & 3) << 4;
  const int rowB = 3 * DIM;
  const int ntile = qblk + 1;
  // Q stage (wave-local rows)
  {
    const u16* qp = base + (size_t)(q0 + sr) * rowB + h * DHEAD + sd;
    *(bf16x8*)&QPs[sr][sd] = *(const bf16x8*)(const void*)qp;
    *(bf16x8*)&QPs[sr][sd + 8] = *(const bf16x8*)(const void*)(qp + 8);
  }
  // K/V tile 0 -> regs -> LDS buffer 0 (pre-loop)
  const u16* kp0 = base + (size_t)sr * rowB + DIM + h * DHEAD + sd;
  const u16* vp0 = base + (size_t)sr * rowB + 2 * DIM + h * DHEAD + sd;
  bf16x8 kR0 = *(const bf16x8*)(const void*)kp0;
  bf16x8 kR1 = *(const bf16x8*)(const void*)(kp0 + 8);
  bf16x8 vR0 = *(const bf16x8*)(const void*)vp0;
  bf16x8 vR1 = *(const bf16x8*)(const void*)(vp0 + 8);
  *(bf16x8*)&Ks[0][sr][sd] = kR0;
  *(bf16x8*)&Ks[0][sr][sd + 8] = kR1;
#pragma unroll
  for (int e = 0; e < 8; ++e) Vs[0][sd + e][sr] = vR0[e];
#pragma unroll
  for (int e = 0; e < 8; ++e) Vs[0][sd + 8 + e][sr] = vR1[e];
  __syncthreads();   // S0: Q + KV[0] visible
  bf16x8 aQ0 = *(const bf16x8*)&QPs[w * 16 + l16][quad * 8];
  bf16x8 aQ1 = *(const bf16x8*)&QPs[w * 16 + l16][32 + quad * 8];
  f32x4 accO[4];
#pragma unroll
  for (int j = 0; j < 4; ++j) accO[j] = (f32x4){0.f, 0.f, 0.f, 0.f};
  float mSt[4] = {-1e30f, -1e30f, -1e30f, -1e30f};
  float lSt[4] = {0.f, 0.f, 0.f, 0.f};
  for (int kt = 0; kt < ntile; ++kt) {
    const int cur = kt & 1;
    if (kt > 0) __syncthreads();   // single barrier: KV[cur] stores visible,
                                   // prior readers of KV[cur^1] done
    if (kt + 1 < ntile) {   // issue next-tile loads (consumed at end of iter)
      const u16* kp = kp0 + (size_t)(kt + 1) * 64 * rowB;
      const u16* vp = vp0 + (size_t)(kt + 1) * 64 * rowB;
      kR0 = *(const bf16x8*)(const void*)kp;
      kR1 = *(const bf16x8*)(const void*)(kp + 8);
      vR0 = *(const bf16x8*)(const void*)vp;
      vR1 = *(const bf16x8*)(const void*)(vp + 8);
    }
    f32x4 s[4];
#pragma unroll
    for (int j = 0; j < 4; ++j) {
      bf16x8 b0 = *(const bf16x8*)&Ks[cur][j * 16 + l16][quad * 8];
      bf16x8 b1 = *(const bf16x8*)&Ks[cur][j * 16 + l16][32 + quad * 8];
      s[j] = (f32x4){0.f, 0.f, 0.f, 0.f};
      s[j] = MFMA16(aQ0, b0, s[j]);
      s[j] = MFMA16(aQ1, b1, s[j]);
      s[j] *= 0.125f;
    }
#pragma unroll
    for (int reg = 0; reg < 4; ++reg) {
      float mx = fmaxf(fmaxf(s[0][reg], s[1][reg]), fmaxf(s[2][reg], s[3][reg]));
      mx = fmaxf(mx, __shfl_xor(mx, 1));
      mx = fmaxf(mx, __shfl_xor(mx, 2));
      mx = fmaxf(mx, __shfl_xor(mx, 4));
      mx = fmaxf(mx, __shfl_xor(mx, 8));
      float mNew = fmaxf(mSt[reg], mx);
      float alpha = __expf(mSt[reg] - mNew);
      mSt[reg] = mNew;
      float rs = 0.f;
#pragma unroll
      for (int j = 0; j < 4; ++j) {
        float p = __expf(s[j][reg] - mNew);
        s[j][reg] = p;
        rs += p;
      }
      rs += __shfl_xor(rs, 1);
      rs += __shfl_xor(rs, 2);
      rs += __shfl_xor(rs, 4);
      rs += __shfl_xor(rs, 8);
      lSt[reg] = lSt[reg] * alpha + rs;
#pragma unroll
      for (int j = 0; j < 4; ++j) accO[j][reg] *= alpha;
    }
    // P transpose via wave-local LDS rows (no barrier needed)
#pragma unroll
    for (int j = 0; j < 4; ++j)
#pragma unroll
      for (int reg = 0; reg < 4; ++reg)
        *(u16*)&QPs[w * 16 + quad * 4 + reg][j * 16 + l16] = f2b(s[j][reg]);
    // store next K/V tile into the other parity buffer (covers load latency
    // with the QK^T+softmax above; visibility at next iteration's barrier)
    if (kt + 1 < ntile) {
      const int nxt = cur ^ 1;
      *(bf16x8*)&Ks[nxt][sr][sd] = kR0;
      *(bf16x8*)&Ks[nxt][sr][sd + 8] = kR1;
#pragma unroll
      for (int e = 0; e < 8; ++e) Vs[nxt][sd + e][sr] = vR0[e];
#pragma unroll
      for (int e = 0; e < 8; ++e) Vs[nxt][sd + 8 + e][sr] = vR1[e];
    }
    bf16x8 aP0 = *(const bf16x8*)&QPs[w * 16 + l16][quad * 8];
    bf16x8 aP1 = *(const bf16x8*)&QPs[w * 16 + l16][32 + quad * 8];
#pragma unroll
    for (int jd = 0; jd < 4; ++jd) {
      bf16x8 b0 = *(const bf16x8*)&Vs[cur][jd * 16 + l16][quad * 8];
      bf16x8 b1 = *(const bf16x8*)&Vs[cur][jd * 16 + l16][32 + quad * 8];
      accO[jd] = MFMA16(aP0, b0, accO[jd]);
      accO[jd] = MFMA16(aP1, b1, accO[jd]);
    }
  }
#pragma unroll
  for (int reg = 0; reg < 4; ++reg) {
    float inv = 1.0f / lSt[reg];
    int row = q0 + w * 16 + quad * 4 + reg;
#pragma unroll
    for (int jd = 0; jd < 4; ++jd)
      o[((size_t)(b * SEQ + row)) * DIM + h * DHEAD + jd * 16 + l16] =
          f2b(accO[jd][reg] * inv);
  }
}

// ---------------- reduce + bias + residual + LayerNorm, vectorized.
// 2 rows/block; 128 threads/row; float4/ushort4 accesses. part indexed by r.
// GIN: residual f_in is full-layout, gathered via init-slot map (layer-5 LN1).
template <int GIN>
__global__ __launch_bounds__(256) void k_red_ln(const float* __restrict__ part,
                                                const float* __restrict__ bias,
                                                const float* __restrict__ f_in,
                                                float* __restrict__ f_out,
                                                u16* __restrict__ fb_out,
                                                const float* __restrict__ s,
                                                const float* __restrict__ bvec) {
  const int t = threadIdx.x;
  const int half = t >> 7;                 // row within pair
  const int r = blockIdx.x * 2 + half;
  const int c = (t & 127) * 4;
  int g = r;
  if (GIN) {
    int p = r & 63, pr = (r >> 6) % PAIRS, b = r / (PAIRS * PP);
    g = b * SEQ + pr * 128 + p;
  }
  float4 x = *(const float4*)(f_in + (size_t)g * DIM + c);
  float4 pa = *(const float4*)(part + (size_t)r * DIM + c);
  float4 bi = *(const float4*)(bias + c);
  x.x += pa.x + bi.x; x.y += pa.y + bi.y; x.z += pa.z + bi.z; x.w += pa.w + bi.w;
  float sum = x.x + x.y + x.z + x.w;
  float sq = x.x * x.x + x.y * x.y + x.z * x.z + x.w * x.w;
#pragma unroll
  for (int off = 32; off; off >>= 1) {
    sum += __shfl_xor(sum, off);
    sq += __shfl_xor(sq, off);
  }
  __shared__ float rs[4], rq[4];
  const int w = t >> 6, lane = t & 63;
  if (lane == 0) { rs[w] = sum; rq[w] = sq; }
  __syncthreads();
  float tot = rs[half * 2] + rs[half * 2 + 1];
  float tq2 = rq[half * 2] + rq[half * 2 + 1];
  float mu = tot * (1.0f / 512.0f);
  float var = tq2 * (1.0f / 512.0f) - mu * mu;
  float rstd = rsqrtf(var + 1e-5f);
  float4 sv = *(const float4*)(s + c);
  float4 bv = *(const float4*)(bvec + c);
  float4 o;
  o.x = (x.x - mu) * rstd * sv.x + bv.x;
  o.y = (x.y - mu) * rstd * sv.y + bv.y;
  o.z = (x.z - mu) * rstd * sv.z + bv.z;
  o.w = (x.w - mu) * rstd * sv.w + bv.w;
  *(float4*)(f_out + (size_t)r * DIM + c) = o;
  u16x4 ob;
  ob[0] = f2b(o.x); ob[1] = f2b(o.y); ob[2] = f2b(o.z); ob[3] = f2b(o.w);
  *(u16x4*)(fb_out + (size_t)r * DIM + c) = ob;
}

extern "C" void kernel_launch(void* const* d_in, const int* in_sizes, int n_in,
                              void* d_out, int out_size, void* d_ws, size_t ws_size,
                              hipStream_t stream) {
  const float* init = (const float*)d_in[0];
  const float* endp = (const float*)d_in[1];
  const float* pre_W = (const float*)d_in[3];
  const float* pre_b = (const float*)d_in[4];
  const float* post_W = (const float*)d_in[5];
  const float* post_b = (const float*)d_in[6];
  const float* patch_pos = (const float*)d_in[7];
  const float* func_pos = (const float*)d_in[8];
  const float* Wqkv = (const float*)d_in[9];
  const float* bqkv = (const float*)d_in[10];
  const float* Wo = (const float*)d_in[11];
  const float* bo = (const float*)d_in[12];
  const float* ln1_s = (const float*)d_in[13];
  const float* ln1_b = (const float*)d_in[14];
  const float* ln2_s = (const float*)d_in[15];
  const float* ln2_b = (const float*)d_in[16];
  const float* W1 = (const float*)d_in[17];
  const float* b1 = (const float*)d_in[18];
  const float* W2 = (const float*)d_in[19];
  const float* b2 = (const float*)d_in[20];
  float* out = (float*)d_out;

  // ws layout (~110 MB; ws is 256 MB)
  char* p = (char*)d_ws;
  float* buf_f = (float*)p;    p += (size_t)NTOK * DIM * 4;    // f32 residual master
  u16* buf_fb = (u16*)p;       p += (size_t)NTOK * DIM * 2;    // bf16 stream
  u16* buf_attn = (u16*)p;     p += (size_t)NTOK * DIM * 2;
  u16* shared_b = (u16*)p;     p += (size_t)NTOK * DFF * 2;    // patch/qkv/hid alias
  u16* wAll = (u16*)p;         p += (size_t)N_CVT * 2;         // ALL weights bf16
  float* partial = (float*)p;  p += (size_t)NTOK * DIM * 4;
  float* buf_fc = (float*)p;   p += (size_t)MPOST * DIM * 4;   // layer-5 compact f32
  u16* buf_fbc = (u16*)p;      p += (size_t)MPOST * DIM * 2;   // layer-5 compact bf16
  u16* buf_patch = shared_b;
  u16* buf_qkv = shared_b;
  u16* buf_hid = shared_b;
  u16* wPre = wAll;
  u16* wPost = wAll + DIM * DIM;
  u16* wL = wAll + PREPOST;

  dim3 blk(256);
  const int elems = NTOK * DIM;

  k_cvt_all<<<N_CVT / (256 * 8), blk, 0, stream>>>(pre_W, post_W, Wqkv, Wo, W1, W2,
                                                   wAll);
  k_patchify<<<elems / 256, blk, 0, stream>>>(init, endp, buf_patch);
  // pre GEMM fused with bias+pos epilogue -> buf_f (f32) + buf_fb (bf16)
  k_mma<2, 0><<<dim3(8, 80), blk, 0, stream>>>(
      buf_patch, wPre, pre_b, buf_fb, nullptr, buf_f, patch_pos, func_pos,
      NTOK, DIM, DIM, 0);

  for (int l = 0; l < NLAYER; ++l) {
    u16* wB = wL + (size_t)l * W_ALL;
    // QKV: 64x64 tiles — grid (24,80)
    k_mma<0, 0><<<dim3(24, 80), blk, 0, stream>>>(
        buf_fb, wB, bqkv + (size_t)l * 3 * DIM, buf_qkv, nullptr, nullptr, nullptr,
        nullptr, NTOK, 3 * DIM, DIM, 0);
    if (l < NLAYER - 1) {
      k_attn<<<dim3(SEQ / 64, NHEAD, BSZ), blk, 0, stream>>>(buf_qkv, buf_attn, 1);
      k_mma<1, 0><<<dim3(8, 80), blk, 0, stream>>>(
          buf_attn, wB + OFF_O, nullptr, nullptr, partial, nullptr, nullptr, nullptr,
          NTOK, DIM, DIM, 0);
      k_red_ln<0><<<NTOK / 2, blk, 0, stream>>>(partial, bo + (size_t)l * DIM,
                                                buf_f, buf_f, buf_fb,
                                                ln1_s + (size_t)l * DIM,
                                                ln1_b + (size_t)l * DIM);
      // FF1: 64x64 tiles — grid (32,80)
      k_mma<0, 0><<<dim3(32, 80), blk, 0, stream>>>(
          buf_fb, wB + OFF_1, b1 + (size_t)l * DFF, buf_hid, nullptr, nullptr,
          nullptr, nullptr, NTOK, DFF, DIM, 1);
      k_mma<1, 0><<<dim3(8, 80), blk, 0, stream>>>(
          buf_hid, wB + OFF_2, nullptr, nullptr, partial, nullptr, nullptr, nullptr,
          NTOK, DIM, DFF, 0);
      k_red_ln<0><<<NTOK / 2, blk, 0, stream>>>(partial, b2 + (size_t)l * DIM,
                                                buf_f, buf_f, buf_fb,
                                                ln2_s + (size_t)l * DIM,
                                                ln2_b + (size_t)l * DIM);
    } else {
      // layer 5: only init-slot rows matter downstream (exact trim)
      k_attn<<<dim3(SEQ / 128, NHEAD, BSZ), blk, 0, stream>>>(buf_qkv, buf_attn, 2);
      k_mma<1, 1><<<dim3(8, 40), blk, 0, stream>>>(     // proj, gathered A
          buf_attn, wB + OFF_O, nullptr, nullptr, partial, nullptr, nullptr, nullptr,
          MPOST, DIM, DIM, 0);
      k_red_ln<1><<<MPOST / 2, blk, 0, stream>>>(partial, bo + (size_t)l * DIM,
                                                 buf_f, buf_fc, buf_fbc,
                                                 ln1_s + (size_t)l * DIM,
                                                 ln1_b + (size_t)l * DIM);
      // FF1 l5 — grid (32,40)
      k_mma<0, 0><<<dim3(32, 40), blk, 0, stream>>>(
          buf_fbc, wB + OFF_1, b1 + (size_t)l * DFF, buf_hid, nullptr, nullptr,
          nullptr, nullptr, MPOST, DFF, DIM, 1);
      k_mma<1, 0><<<dim3(8, 40), blk, 0, stream>>>(
          buf_hid, wB + OFF_2, nullptr, nullptr, partial, nullptr, nullptr, nullptr,
          MPOST, DIM, DFF, 0);
      k_red_ln<0><<<MPOST / 2, blk, 0, stream>>>(partial, b2 + (size_t)l * DIM,
                                                 buf_fc, buf_fc, buf_fbc,
                                                 ln2_s + (size_t)l * DIM,
                                                 ln2_b + (size_t)l * DIM);
    }
  }

  // post GEMM: compact A rows + bias + depatchify scatter (epilogue)
  k_mma<3, 0><<<dim3(8, 40), blk, 0, stream>>>(
      buf_fbc, wPost, post_b, nullptr, nullptr, out, nullptr, nullptr,
      MPOST, DIM, DIM, 0);
}

// Round 12
// 863.342 us; speedup vs baseline: 1.1548x; 1.1548x over previous
//
#include <hip/hip_runtime.h>
#include <hip/hip_bf16.h>

#define BSZ 8
#define PAIRS 5
#define NCH 2
#define HWP 128
#define PP 64
#define DIM 512
#define NHEAD 8
#define DHEAD 64
#define DFF 2048
#define NLAYER 6
#define SEQ 640
#define NTOK (BSZ * SEQ)   // 5120
#define FIN 10
#define MPOST (BSZ * PAIRS * PP)   // 2560

typedef unsigned short u16;
typedef __bf16 bf16_t;
typedef __attribute__((ext_vector_type(8))) __bf16 bf16x8;
typedef __attribute__((ext_vector_type(8))) unsigned short u16x8;
typedef __attribute__((ext_vector_type(4))) unsigned short u16x4;
typedef __attribute__((ext_vector_type(4))) float f32x4;
#define MFMA16(a, b, c) __builtin_amdgcn_mfma_f32_16x16x32_bf16(a, b, c, 0, 0, 0)

__device__ __forceinline__ u16 f2b(float x) {   // RNE f32->bf16
  unsigned u = __float_as_uint(x);
  return (u16)((u + 0x7fffu + ((u >> 16) & 1u)) >> 16);
}

// tanh-form GELU (error vs exact erf-GELU <~1e-3; margin is 0.032)
__device__ __forceinline__ float gelu_t(float x) {
  float y = 0.7978845608f * (x + 0.044715f * x * x * x);
  y = fminf(fmaxf(y, -10.f), 10.f);
  float e = __expf(2.f * y);
  return 0.5f * x * (1.f + (e - 1.f) / (e + 1.f));
}

// async global->LDS DMA, 16B/lane; LDS dest = wave-uniform base + lane*16
__device__ __forceinline__ void dma16(const u16* g, void* l) {
  __builtin_amdgcn_global_load_lds(
      (const __attribute__((address_space(1))) void*)g,
      (__attribute__((address_space(3))) void*)l, 16, 0, 0);
}

template <int N> __device__ __forceinline__ void vwait() {
  if constexpr (N == 0) asm volatile("s_waitcnt vmcnt(0)" ::: "memory");
  else if constexpr (N == 2) asm volatile("s_waitcnt vmcnt(2)" ::: "memory");
  else if constexpr (N == 3) asm volatile("s_waitcnt vmcnt(3)" ::: "memory");
  else if constexpr (N == 4) asm volatile("s_waitcnt vmcnt(4)" ::: "memory");
  else if constexpr (N == 6) asm volatile("s_waitcnt vmcnt(6)" ::: "memory");
}

#define W_QKV (3 * DIM * DIM)   // 786432
#define W_O (DIM * DIM)         // 262144
#define W_1 (DFF * DIM)         // 1048576
#define OFF_O W_QKV
#define OFF_1 (W_QKV + W_O)
#define OFF_2 (W_QKV + W_O + W_1)
#define W_ALL (W_QKV + W_O + 2 * W_1)   // 3145728
#define PREPOST (2 * DIM * DIM)         // 524288
#define N_CVT (PREPOST + NLAYER * W_ALL)   // 19398656

// ---------------- ALL weights f32->bf16, 8 elems/thread, 16B stores
__global__ __launch_bounds__(256) void k_cvt_all(const float* __restrict__ preW,
                                                 const float* __restrict__ postW,
                                                 const float* __restrict__ wq,
                                                 const float* __restrict__ wo,
                                                 const float* __restrict__ w1,
                                                 const float* __restrict__ w2,
                                                 u16* __restrict__ dst) {
  size_t i = ((size_t)blockIdx.x * 256 + threadIdx.x) * 8;   // < N_CVT
  const float* src;
  size_t off;
  if (i < DIM * DIM) { src = preW; off = i; }
  else if (i < PREPOST) { src = postW; off = i - DIM * DIM; }
  else {
    size_t j = i - PREPOST;
    int l = (int)(j / W_ALL);
    size_t r = j - (size_t)l * W_ALL;
    if (r < OFF_O) { src = wq + (size_t)l * W_QKV; off = r; }
    else if (r < OFF_1) { src = wo + (size_t)l * W_O; off = r - OFF_O; }
    else if (r < OFF_2) { src = w1 + (size_t)l * W_1; off = r - OFF_1; }
    else { src = w2 + (size_t)l * W_1; off = r - OFF_2; }
  }
  float4 v0 = *(const float4*)(src + off);
  float4 v1 = *(const float4*)(src + off + 4);
  u16x8 o;
  o[0] = f2b(v0.x); o[1] = f2b(v0.y); o[2] = f2b(v0.z); o[3] = f2b(v0.w);
  o[4] = f2b(v1.x); o[5] = f2b(v1.y); o[6] = f2b(v1.z); o[7] = f2b(v1.w);
  *(u16x8*)(dst + i) = o;
}

// ---------------- patchify -> bf16 A[NTOK][512]
__global__ __launch_bounds__(256) void k_patchify(const float* __restrict__ init,
                                                  const float* __restrict__ endp,
                                                  u16* __restrict__ A) {
  int i = blockIdx.x * 256 + threadIdx.x;
  int d = i & 511;
  int g = i >> 9;
  int p = g & 63;
  int fi = (g >> 6) % FIN;
  int b = g / SEQ;
  int e = fi & 1;
  int pr = fi >> 1;
  int c = d >> 8;
  int r1 = (d >> 4) & 15;
  int r2 = d & 15;
  int row = ((p >> 3) << 4) + r1;
  int col = ((p & 7) << 4) + r2;
  const float* src = e ? endp : init;
  size_t off = ((size_t)((b * PAIRS + pr) * NCH + c) << 14) + (size_t)row * HWP + col;
  A[i] = f2b(src[off]);
}

// ---------------- bf16 MFMA GEMM, 4-buffer DMA pipeline, ONE s_barrier/iter
// (R4 verified-best), BK=32 (R7 BK=64, R8 split-K, R11 zero-barrier-private
// all regressed). vmcnt(2*NC) before the barrier waits only the tile
// consumed now. BY-MAJOR XCD swizzle (R5): each XCD owns gy/8 contiguous
// row-bands -> A fetched once per chip, per-XCD set ~L2-resident.
// Tile BM(M) x NT(N), BK=32, 4 waves 2x2.
// MODE 0: outB = act(A·B^T + bias) bf16
// MODE 1: outP = raw f32 partial
// MODE 2: pre epilogue: +bias+patch_pos+func_pos -> outF f32 + outB bf16
// MODE 3: post epilogue: +bias, depatchify scatter -> outF (A compact rows)
// GATHER: A rows are init-slot tokens of a full-layout buffer
template <int BM, int NT, int MODE, int GATHER>
__global__ __launch_bounds__(256) void k_mma(const u16* __restrict__ A,
                                             const u16* __restrict__ B,
                                             const float* __restrict__ bias,
                                             u16* __restrict__ outB,
                                             float* __restrict__ outP,
                                             float* __restrict__ outF,
                                             const float* __restrict__ pp,
                                             const float* __restrict__ fp,
                                             int M, int N, int K, int act) {
  constexpr int FJ = NT / 32;                  // N-frags per wave
  constexpr int MI = BM / 32;                  // M-frags per wave
  constexpr int ACH = BM / 16;                 // A DMA chunks (16 rows each)
  constexpr int NC = (BM / 16 + NT / 16) / 4;  // DMA instrs per wave per stage
  __shared__ __align__(16) bf16_t As[4][BM][32];
  __shared__ __align__(16) bf16_t Bs[4][NT][32];
  const int t = threadIdx.x;
  const int w = t >> 6, lane = t & 63, quad = lane >> 4, l16 = lane & 15;
  int bx = blockIdx.x, by = blockIdx.y;
  if ((gridDim.y & 7) == 0) {       // by-major XCD swizzle (A-row locality)
    int lin = bx + gridDim.x * by;
    int xcd = lin & 7, slot = lin >> 3;
    int gx = gridDim.x;
    by = (gridDim.y >> 3) * xcd + slot / gx;
    bx = slot % gx;
  }
  const int row0 = by * BM, col0 = bx * NT;
  const int mB = (w & 1) * (BM / 2);
  const int nB = (w >> 1) * (NT / 2);

  // per-lane A-chunk source pointers
  const u16* aP[ACH];
#pragma unroll
  for (int c = 0; c < ACH; ++c) {
    int r = row0 + c * 16 + (lane >> 2);
    int g = r;
    if (GATHER) {
      int p = r & 63, pr = (r >> 6) % PAIRS, b = r / (PAIRS * PP);
      g = b * SEQ + pr * 128 + p;
    }
    aP[c] = A + (size_t)g * K + ((lane & 3) << 3);
  }
  const u16* bP = B + (size_t)(col0 + (lane >> 2)) * K + ((lane & 3) << 3);

  f32x4 acc[MI][FJ];
#pragma unroll
  for (int i = 0; i < MI; ++i)
#pragma unroll
    for (int j = 0; j < FJ; ++j) acc[i][j] = (f32x4){0.f, 0.f, 0.f, 0.f};

  auto stage = [&](int bu, int kk) {
#pragma unroll
    for (int s = 0; s < NC; ++s) {
      int c = NC * w + s;
      if (c < ACH) dma16(aP[c] + kk, &As[bu][c * 16][0]);
      else dma16(bP + (size_t)((c - ACH) * 16) * K + kk, &Bs[bu][(c - ACH) * 16][0]);
    }
  };

  const int iters = K >> 5;
  stage(0, 0);
  stage(1, 32);
  for (int it = 0; it < iters; ++it) {
    const int cur = it & 3;
    if (it + 2 < iters) stage((it + 2) & 3, (it + 2) << 5);  // stays in flight
    if (it + 2 < iters) vwait<2 * NC>();
    else if (it + 1 < iters) vwait<NC>();
    else vwait<0>();
    asm volatile("s_barrier" ::: "memory");   // single barrier: cur DMAs landed
    bf16x8 af[MI], bfr[FJ];
#pragma unroll
    for (int i = 0; i < MI; ++i)
      af[i] = *(const bf16x8*)&As[cur][mB + i * 16 + l16][quad * 8];
#pragma unroll
    for (int j = 0; j < FJ; ++j)
      bfr[j] = *(const bf16x8*)&Bs[cur][nB + j * 16 + l16][quad * 8];
#pragma unroll
    for (int i = 0; i < MI; ++i)
#pragma unroll
      for (int j = 0; j < FJ; ++j) acc[i][j] = MFMA16(af[i], bfr[j], acc[i][j]);
  }

#pragma unroll
  for (int i = 0; i < MI; ++i)
#pragma unroll
    for (int reg = 0; reg < 4; ++reg) {
      int m = row0 + mB + i * 16 + quad * 4 + reg;
#pragma unroll
      for (int j = 0; j < FJ; ++j) {
        int n = col0 + nB + j * 16 + l16;
        float v = acc[i][j][reg];
        if (MODE == 0) {
          v += bias[n];
          if (act) v = gelu_t(v);
          outB[(size_t)m * N + n] = f2b(v);
        } else if (MODE == 1) {
          outP[(size_t)m * N + n] = v;
        } else if (MODE == 2) {
          int p = m & 63, fi = (m >> 6) % FIN;
          v += bias[n] + pp[p * DIM + n] + fp[fi * DIM + n];
          outF[(size_t)m * N + n] = v;
          outB[(size_t)m * N + n] = f2b(v);
        } else {   // MODE 3: depatchify scatter (A/m compact init rows)
          v += bias[n];
          int p = m & 63, pr = (m >> 6) % PAIRS, b = m / (PAIRS * PP);
          int c = n >> 8, r1 = (n >> 4) & 15, r2 = n & 15;
          int row = ((p >> 3) << 4) + r1, col = ((p & 7) << 4) + r2;
          size_t off = ((size_t)((b * PAIRS + pr) * NCH + c) << 14) +
                       (size_t)row * HWP + col;
          outF[off] = v;
        }
      }
    }
}

// ---------------- fused flash attention (bf16 MFMA), ONE barrier per K-tile.
// R10 barrier audit: Ps and Qs are WAVE-LOCAL (rows [16w,16w+16) written and
// read by wave w only) -> softmax->PV sync and Q-stage sync unnecessary.
// K/V double-buffered: store tile kt+1 into parity buffer cur^1 (R4-style
// safety). LPT dispatch (R9): qblk reversed so heaviest blocks launch first.
// qmul: q-block stride (layer 5 only needs even q-blocks -> qmul=2)
__global__ __launch_bounds__(256) void k_attn(const u16* __restrict__ qkv,
                                              u16* __restrict__ o, int qmul) {
  __shared__ bf16_t Ks[2][64][72];
  __shared__ bf16_t Vs[2][64][72];   // transposed: Vs[.][d][tok]
  __shared__ bf16_t QPs[64][72];     // Q staging, then P transpose (wave-local)
  const int t = threadIdx.x;
  const int w = t >> 6, lane = t & 63, quad = lane >> 4, l16 = lane & 15;
  const int qblk = ((int)gridDim.x - 1 - (int)blockIdx.x) * qmul;  // LPT order
  const int h = blockIdx.y, b = blockIdx.z;
  const int q0 = qblk << 6;
  const u16* base = qkv + (size_t)b * SEQ * (3 * DIM);
  const int sr = t >> 2;
  const int sd = (t & 3) << 4;
  const int rowB = 3 * DIM;
  const int ntile = qblk + 1;
  // Q stage (wave-local rows)
  {
    const u16* qp = base + (size_t)(q0 + sr) * rowB + h * DHEAD + sd;
    *(bf16x8*)&QPs[sr][sd] = *(const bf16x8*)(const void*)qp;
    *(bf16x8*)&QPs[sr][sd + 8] = *(const bf16x8*)(const void*)(qp + 8);
  }
  // K/V tile 0 -> regs -> LDS buffer 0 (pre-loop)
  const u16* kp0 = base + (size_t)sr * rowB + DIM + h * DHEAD + sd;
  const u16* vp0 = base + (size_t)sr * rowB + 2 * DIM + h * DHEAD + sd;
  bf16x8 kR0 = *(const bf16x8*)(const void*)kp0;
  bf16x8 kR1 = *(const bf16x8*)(const void*)(kp0 + 8);
  bf16x8 vR0 = *(const bf16x8*)(const void*)vp0;
  bf16x8 vR1 = *(const bf16x8*)(const void*)(vp0 + 8);
  *(bf16x8*)&Ks[0][sr][sd] = kR0;
  *(bf16x8*)&Ks[0][sr][sd + 8] = kR1;
#pragma unroll
  for (int e = 0; e < 8; ++e) Vs[0][sd + e][sr] = vR0[e];
#pragma unroll
  for (int e = 0; e < 8; ++e) Vs[0][sd + 8 + e][sr] = vR1[e];
  __syncthreads();   // S0: Q + KV[0] visible
  bf16x8 aQ0 = *(const bf16x8*)&QPs[w * 16 + l16][quad * 8];
  bf16x8 aQ1 = *(const bf16x8*)&QPs[w * 16 + l16][32 + quad * 8];
  f32x4 accO[4];
#pragma unroll
  for (int j = 0; j < 4; ++j) accO[j] = (f32x4){0.f, 0.f, 0.f, 0.f};
  float mSt[4] = {-1e30f, -1e30f, -1e30f, -1e30f};
  float lSt[4] = {0.f, 0.f, 0.f, 0.f};
  for (int kt = 0; kt < ntile; ++kt) {
    const int cur = kt & 1;
    if (kt > 0) __syncthreads();   // single barrier: KV[cur] stores visible,
                                   // prior readers of KV[cur^1] done
    if (kt + 1 < ntile) {   // issue next-tile loads (consumed at end of iter)
      const u16* kp = kp0 + (size_t)(kt + 1) * 64 * rowB;
      const u16* vp = vp0 + (size_t)(kt + 1) * 64 * rowB;
      kR0 = *(const bf16x8*)(const void*)kp;
      kR1 = *(const bf16x8*)(const void*)(kp + 8);
      vR0 = *(const bf16x8*)(const void*)vp;
      vR1 = *(const bf16x8*)(const void*)(vp + 8);
    }
    f32x4 s[4];
#pragma unroll
    for (int j = 0; j < 4; ++j) {
      bf16x8 b0 = *(const bf16x8*)&Ks[cur][j * 16 + l16][quad * 8];
      bf16x8 b1 = *(const bf16x8*)&Ks[cur][j * 16 + l16][32 + quad * 8];
      s[j] = (f32x4){0.f, 0.f, 0.f, 0.f};
      s[j] = MFMA16(aQ0, b0, s[j]);
      s[j] = MFMA16(aQ1, b1, s[j]);
      s[j] *= 0.125f;
    }
#pragma unroll
    for (int reg = 0; reg < 4; ++reg) {
      float mx = fmaxf(fmaxf(s[0][reg], s[1][reg]), fmaxf(s[2][reg], s[3][reg]));
      mx = fmaxf(mx, __shfl_xor(mx, 1));
      mx = fmaxf(mx, __shfl_xor(mx, 2));
      mx = fmaxf(mx, __shfl_xor(mx, 4));
      mx = fmaxf(mx, __shfl_xor(mx, 8));
      float mNew = fmaxf(mSt[reg], mx);
      float alpha = __expf(mSt[reg] - mNew);
      mSt[reg] = mNew;
      float rs = 0.f;
#pragma unroll
      for (int j = 0; j < 4; ++j) {
        float p = __expf(s[j][reg] - mNew);
        s[j][reg] = p;
        rs += p;
      }
      rs += __shfl_xor(rs, 1);
      rs += __shfl_xor(rs, 2);
      rs += __shfl_xor(rs, 4);
      rs += __shfl_xor(rs, 8);
      lSt[reg] = lSt[reg] * alpha + rs;
#pragma unroll
      for (int j = 0; j < 4; ++j) accO[j][reg] *= alpha;
    }
    // P transpose via wave-local LDS rows (no barrier needed)
#pragma unroll
    for (int j = 0; j < 4; ++j)
#pragma unroll
      for (int reg = 0; reg < 4; ++reg)
        *(u16*)&QPs[w * 16 + quad * 4 + reg][j * 16 + l16] = f2b(s[j][reg]);
    // store next K/V tile into the other parity buffer (covers load latency
    // with the QK^T+softmax above; visibility at next iteration's barrier)
    if (kt + 1 < ntile) {
      const int nxt = cur ^ 1;
      *(bf16x8*)&Ks[nxt][sr][sd] = kR0;
      *(bf16x8*)&Ks[nxt][sr][sd + 8] = kR1;
#pragma unroll
      for (int e = 0; e < 8; ++e) Vs[nxt][sd + e][sr] = vR0[e];
#pragma unroll
      for (int e = 0; e < 8; ++e) Vs[nxt][sd + 8 + e][sr] = vR1[e];
    }
    bf16x8 aP0 = *(const bf16x8*)&QPs[w * 16 + l16][quad * 8];
    bf16x8 aP1 = *(const bf16x8*)&QPs[w * 16 + l16][32 + quad * 8];
#pragma unroll
    for (int jd = 0; jd < 4; ++jd) {
      bf16x8 b0 = *(const bf16x8*)&Vs[cur][jd * 16 + l16][quad * 8];
      bf16x8 b1 = *(const bf16x8*)&Vs[cur][jd * 16 + l16][32 + quad * 8];
      accO[jd] = MFMA16(aP0, b0, accO[jd]);
      accO[jd] = MFMA16(aP1, b1, accO[jd]);
    }
  }
#pragma unroll
  for (int reg = 0; reg < 4; ++reg) {
    float inv = 1.0f / lSt[reg];
    int row = q0 + w * 16 + quad * 4 + reg;
#pragma unroll
    for (int jd = 0; jd < 4; ++jd)
      o[((size_t)(b * SEQ + row)) * DIM + h * DHEAD + jd * 16 + l16] =
          f2b(accO[jd][reg] * inv);
  }
}

// ---------------- reduce + bias + residual + LayerNorm, WAVE-PER-ROW (R12):
// 4 rows/block, one row per wave; lane covers 8 cols (2x float4) -> 512 =
// 64 lanes x 8. Row reduction is a pure 6-step __shfl_xor over the wave —
// NO LDS, NO __syncthreads (the R4/R10 sync-removal mechanism applied to the
// last remaining barrier in the graph). Vectorized loads/stores unchanged.
// GIN: residual f_in is full-layout, gathered via init-slot map (layer-5 LN1).
template <int GIN>
__global__ __launch_bounds__(256) void k_red_ln(const float* __restrict__ part,
                                                const float* __restrict__ bias,
                                                const float* __restrict__ f_in,
                                                float* __restrict__ f_out,
                                                u16* __restrict__ fb_out,
                                                const float* __restrict__ s,
                                                const float* __restrict__ bvec) {
  const int t = threadIdx.x;
  const int w = t >> 6, lane = t & 63;
  const int r = blockIdx.x * 4 + w;
  const int c = lane * 8;
  int g = r;
  if (GIN) {
    int p = r & 63, pr = (r >> 6) % PAIRS, b = r / (PAIRS * PP);
    g = b * SEQ + pr * 128 + p;
  }
  float4 x0 = *(const float4*)(f_in + (size_t)g * DIM + c);
  float4 x1 = *(const float4*)(f_in + (size_t)g * DIM + c + 4);
  float4 p0 = *(const float4*)(part + (size_t)r * DIM + c);
  float4 p1 = *(const float4*)(part + (size_t)r * DIM + c + 4);
  float4 b0 = *(const float4*)(bias + c);
  float4 b1 = *(const float4*)(bias + c + 4);
  x0.x += p0.x + b0.x; x0.y += p0.y + b0.y; x0.z += p0.z + b0.z; x0.w += p0.w + b0.w;
  x1.x += p1.x + b1.x; x1.y += p1.y + b1.y; x1.z += p1.z + b1.z; x1.w += p1.w + b1.w;
  float sum = x0.x + x0.y + x0.z + x0.w + x1.x + x1.y + x1.z + x1.w;
  float sq = x0.x * x0.x + x0.y * x0.y + x0.z * x0.z + x0.w * x0.w +
             x1.x * x1.x + x1.y * x1.y + x1.z * x1.z + x1.w * x1.w;
#pragma unroll
  for (int off = 32; off; off >>= 1) {
    sum += __shfl_xor(sum, off);
    sq += __shfl_xor(sq, off);
  }
  float mu = sum * (1.0f / 512.0f);
  float var = sq * (1.0f / 512.0f) - mu * mu;
  float rstd = rsqrtf(var + 1e-5f);
  float4 s0 = *(const float4*)(s + c);
  float4 s1 = *(const float4*)(s + c + 4);
  float4 v0 = *(const float4*)(bvec + c);
  float4 v1 = *(const float4*)(bvec + c + 4);
  float4 o0, o1;
  o0.x = (x0.x - mu) * rstd * s0.x + v0.x;
  o0.y = (x0.y - mu) * rstd * s0.y + v0.y;
  o0.z = (x0.z - mu) * rstd * s0.z + v0.z;
  o0.w = (x0.w - mu) * rstd * s0.w + v0.w;
  o1.x = (x1.x - mu) * rstd * s1.x + v1.x;
  o1.y = (x1.y - mu) * rstd * s1.y + v1.y;
  o1.z = (x1.z - mu) * rstd * s1.z + v1.z;
  o1.w = (x1.w - mu) * rstd * s1.w + v1.w;
  *(float4*)(f_out + (size_t)r * DIM + c) = o0;
  *(float4*)(f_out + (size_t)r * DIM + c + 4) = o1;
  u16x8 ob;
  ob[0] = f2b(o0.x); ob[1] = f2b(o0.y); ob[2] = f2b(o0.z); ob[3] = f2b(o0.w);
  ob[4] = f2b(o1.x); ob[5] = f2b(o1.y); ob[6] = f2b(o1.z); ob[7] = f2b(o1.w);
  *(u16x8*)(fb_out + (size_t)r * DIM + c) = ob;
}

extern "C" void kernel_launch(void* const* d_in, const int* in_sizes, int n_in,
                              void* d_out, int out_size, void* d_ws, size_t ws_size,
                              hipStream_t stream) {
  const float* init = (const float*)d_in[0];
  const float* endp = (const float*)d_in[1];
  const float* pre_W = (const float*)d_in[3];
  const float* pre_b = (const float*)d_in[4];
  const float* post_W = (const float*)d_in[5];
  const float* post_b = (const float*)d_in[6];
  const float* patch_pos = (const float*)d_in[7];
  const float* func_pos = (const float*)d_in[8];
  const float* Wqkv = (const float*)d_in[9];
  const float* bqkv = (const float*)d_in[10];
  const float* Wo = (const float*)d_in[11];
  const float* bo = (const float*)d_in[12];
  const float* ln1_s = (const float*)d_in[13];
  const float* ln1_b = (const float*)d_in[14];
  const float* ln2_s = (const float*)d_in[15];
  const float* ln2_b = (const float*)d_in[16];
  const float* W1 = (const float*)d_in[17];
  const float* b1 = (const float*)d_in[18];
  const float* W2 = (const float*)d_in[19];
  const float* b2 = (const float*)d_in[20];
  float* out = (float*)d_out;

  // ws layout (~110 MB; ws is 256 MB)
  char* p = (char*)d_ws;
  float* buf_f = (float*)p;    p += (size_t)NTOK * DIM * 4;    // f32 residual master
  u16* buf_fb = (u16*)p;       p += (size_t)NTOK * DIM * 2;    // bf16 stream
  u16* buf_attn = (u16*)p;     p += (size_t)NTOK * DIM * 2;
  u16* shared_b = (u16*)p;     p += (size_t)NTOK * DFF * 2;    // patch/qkv/hid alias
  u16* wAll = (u16*)p;         p += (size_t)N_CVT * 2;         // ALL weights bf16
  float* partial = (float*)p;  p += (size_t)NTOK * DIM * 4;
  float* buf_fc = (float*)p;   p += (size_t)MPOST * DIM * 4;   // layer-5 compact f32
  u16* buf_fbc = (u16*)p;      p += (size_t)MPOST * DIM * 2;   // layer-5 compact bf16
  u16* buf_patch = shared_b;
  u16* buf_qkv = shared_b;
  u16* buf_hid = shared_b;
  u16* wPre = wAll;
  u16* wPost = wAll + DIM * DIM;
  u16* wL = wAll + PREPOST;

  dim3 blk(256);
  const int elems = NTOK * DIM;

  k_cvt_all<<<N_CVT / (256 * 8), blk, 0, stream>>>(pre_W, post_W, Wqkv, Wo, W1, W2,
                                                   wAll);
  k_patchify<<<elems / 256, blk, 0, stream>>>(init, endp, buf_patch);
  // pre GEMM fused with bias+pos epilogue -> buf_f (f32) + buf_fb (bf16)
  k_mma<64, 64, 2, 0><<<dim3(8, 80), blk, 0, stream>>>(
      buf_patch, wPre, pre_b, buf_fb, nullptr, buf_f, patch_pos, func_pos,
      NTOK, DIM, DIM, 0);

  for (int l = 0; l < NLAYER; ++l) {
    u16* wB = wL + (size_t)l * W_ALL;
    k_mma<64, 128, 0, 0><<<dim3(12, 80), blk, 0, stream>>>(
        buf_fb, wB, bqkv + (size_t)l * 3 * DIM, buf_qkv, nullptr, nullptr, nullptr,
        nullptr, NTOK, 3 * DIM, DIM, 0);
    if (l < NLAYER - 1) {
      k_attn<<<dim3(SEQ / 64, NHEAD, BSZ), blk, 0, stream>>>(buf_qkv, buf_attn, 1);
      k_mma<64, 64, 1, 0><<<dim3(8, 80), blk, 0, stream>>>(
          buf_attn, wB + OFF_O, nullptr, nullptr, partial, nullptr, nullptr, nullptr,
          NTOK, DIM, DIM, 0);
      k_red_ln<0><<<NTOK / 4, blk, 0, stream>>>(partial, bo + (size_t)l * DIM,
                                                buf_f, buf_f, buf_fb,
                                                ln1_s + (size_t)l * DIM,
                                                ln1_b + (size_t)l * DIM);
      k_mma<64, 128, 0, 0><<<dim3(16, 80), blk, 0, stream>>>(
          buf_fb, wB + OFF_1, b1 + (size_t)l * DFF, buf_hid, nullptr, nullptr,
          nullptr, nullptr, NTOK, DFF, DIM, 1);
      k_mma<64, 64, 1, 0><<<dim3(8, 80), blk, 0, stream>>>(
          buf_hid, wB + OFF_2, nullptr, nullptr, partial, nullptr, nullptr, nullptr,
          NTOK, DIM, DFF, 0);
      k_red_ln<0><<<NTOK / 4, blk, 0, stream>>>(partial, b2 + (size_t)l * DIM,
                                                buf_f, buf_f, buf_fb,
                                                ln2_s + (size_t)l * DIM,
                                                ln2_b + (size_t)l * DIM);
    } else {
      // layer 5: only init-slot rows matter downstream (exact trim)
      k_attn<<<dim3(SEQ / 128, NHEAD, BSZ), blk, 0, stream>>>(buf_qkv, buf_attn, 2);
      k_mma<64, 64, 1, 1><<<dim3(8, 40), blk, 0, stream>>>(     // proj, gathered A
          buf_attn, wB + OFF_O, nullptr, nullptr, partial, nullptr, nullptr, nullptr,
          MPOST, DIM, DIM, 0);
      k_red_ln<1><<<MPOST / 4, blk, 0, stream>>>(partial, bo + (size_t)l * DIM,
                                                 buf_f, buf_fc, buf_fbc,
                                                 ln1_s + (size_t)l * DIM,
                                                 ln1_b + (size_t)l * DIM);
      k_mma<64, 128, 0, 0><<<dim3(16, 40), blk, 0, stream>>>(
          buf_fbc, wB + OFF_1, b1 + (size_t)l * DFF, buf_hid, nullptr, nullptr,
          nullptr, nullptr, MPOST, DFF, DIM, 1);
      k_mma<64, 64, 1, 0><<<dim3(8, 40), blk, 0, stream>>>(
          buf_hid, wB + OFF_2, nullptr, nullptr, partial, nullptr, nullptr, nullptr,
          MPOST, DIM, DFF, 0);
      k_red_ln<0><<<MPOST / 4, blk, 0, stream>>>(partial, b2 + (size_t)l * DIM,
                                                 buf_fc, buf_fc, buf_fbc,
                                                 ln2_s + (size_t)l * DIM,
                                                 ln2_b + (size_t)l * DIM);
    }
  }

  // post GEMM: compact A rows + bias + depatchify scatter (epilogue)
  k_mma<64, 64, 3, 0><<<dim3(8, 40), blk, 0, stream>>>(
      buf_fbc, wPost, post_b, nullptr, nullptr, out, nullptr, nullptr,
      MPOST, DIM, DIM, 0);
}

// Round 14
// 852.207 us; speedup vs baseline: 1.1699x; 1.0131x over previous
//
#include <hip/hip_runtime.h>
#include <hip/hip_bf16.h>

#define BSZ 8
#define PAIRS 5
#define NCH 2
#define HWP 128
#define PP 64
#define DIM 512
#define NHEAD 8
#define DHEAD 64
#define DFF 2048
#define NLAYER 6
#define SEQ 640
#define NTOK (BSZ * SEQ)   // 5120
#define FIN 10
#define MPOST (BSZ * PAIRS * PP)   // 2560

typedef unsigned short u16;
typedef __bf16 bf16_t;
typedef __attribute__((ext_vector_type(8))) __bf16 bf16x8;
typedef __attribute__((ext_vector_type(8))) unsigned short u16x8;
typedef __attribute__((ext_vector_type(4))) unsigned short u16x4;
typedef __attribute__((ext_vector_type(4))) float f32x4;
#define MFMA16(a, b, c) __builtin_amdgcn_mfma_f32_16x16x32_bf16(a, b, c, 0, 0, 0)

__device__ __forceinline__ u16 f2b(float x) {   // RNE f32->bf16
  unsigned u = __float_as_uint(x);
  return (u16)((u + 0x7fffu + ((u >> 16) & 1u)) >> 16);
}

__device__ __forceinline__ float b2f(u16 x) {   // bf16->f32 (exact)
  return __uint_as_float((unsigned)x << 16);
}

// tanh-form GELU (error vs exact erf-GELU <~1e-3; margin is 0.032)
__device__ __forceinline__ float gelu_t(float x) {
  float y = 0.7978845608f * (x + 0.044715f * x * x * x);
  y = fminf(fmaxf(y, -10.f), 10.f);
  float e = __expf(2.f * y);
  return 0.5f * x * (1.f + (e - 1.f) / (e + 1.f));
}

// async global->LDS DMA, 16B/lane; LDS dest = wave-uniform base + lane*16
__device__ __forceinline__ void dma16(const u16* g, void* l) {
  __builtin_amdgcn_global_load_lds(
      (const __attribute__((address_space(1))) void*)g,
      (__attribute__((address_space(3))) void*)l, 16, 0, 0);
}

template <int N> __device__ __forceinline__ void vwait() {
  if constexpr (N == 0) asm volatile("s_waitcnt vmcnt(0)" ::: "memory");
  else if constexpr (N == 2) asm volatile("s_waitcnt vmcnt(2)" ::: "memory");
  else if constexpr (N == 3) asm volatile("s_waitcnt vmcnt(3)" ::: "memory");
  else if constexpr (N == 4) asm volatile("s_waitcnt vmcnt(4)" ::: "memory");
  else if constexpr (N == 6) asm volatile("s_waitcnt vmcnt(6)" ::: "memory");
}

#define W_QKV (3 * DIM * DIM)   // 786432
#define W_O (DIM * DIM)         // 262144
#define W_1 (DFF * DIM)         // 1048576
#define OFF_O W_QKV
#define OFF_1 (W_QKV + W_O)
#define OFF_2 (W_QKV + W_O + W_1)
#define W_ALL (W_QKV + W_O + 2 * W_1)   // 3145728
#define PREPOST (2 * DIM * DIM)         // 524288
#define N_CVT (PREPOST + NLAYER * W_ALL)   // 19398656

// ---------------- ALL weights f32->bf16, 8 elems/thread, 16B stores
__global__ __launch_bounds__(256) void k_cvt_all(const float* __restrict__ preW,
                                                 const float* __restrict__ postW,
                                                 const float* __restrict__ wq,
                                                 const float* __restrict__ wo,
                                                 const float* __restrict__ w1,
                                                 const float* __restrict__ w2,
                                                 u16* __restrict__ dst) {
  size_t i = ((size_t)blockIdx.x * 256 + threadIdx.x) * 8;   // < N_CVT
  const float* src;
  size_t off;
  if (i < DIM * DIM) { src = preW; off = i; }
  else if (i < PREPOST) { src = postW; off = i - DIM * DIM; }
  else {
    size_t j = i - PREPOST;
    int l = (int)(j / W_ALL);
    size_t r = j - (size_t)l * W_ALL;
    if (r < OFF_O) { src = wq + (size_t)l * W_QKV; off = r; }
    else if (r < OFF_1) { src = wo + (size_t)l * W_O; off = r - OFF_O; }
    else if (r < OFF_2) { src = w1 + (size_t)l * W_1; off = r - OFF_1; }
    else { src = w2 + (size_t)l * W_1; off = r - OFF_2; }
  }
  float4 v0 = *(const float4*)(src + off);
  float4 v1 = *(const float4*)(src + off + 4);
  u16x8 o;
  o[0] = f2b(v0.x); o[1] = f2b(v0.y); o[2] = f2b(v0.z); o[3] = f2b(v0.w);
  o[4] = f2b(v1.x); o[5] = f2b(v1.y); o[6] = f2b(v1.z); o[7] = f2b(v1.w);
  *(u16x8*)(dst + i) = o;
}

// ---------------- patchify -> bf16 A[NTOK][512]
__global__ __launch_bounds__(256) void k_patchify(const float* __restrict__ init,
                                                  const float* __restrict__ endp,
                                                  u16* __restrict__ A) {
  int i = blockIdx.x * 256 + threadIdx.x;
  int d = i & 511;
  int g = i >> 9;
  int p = g & 63;
  int fi = (g >> 6) % FIN;
  int b = g / SEQ;
  int e = fi & 1;
  int pr = fi >> 1;
  int c = d >> 8;
  int r1 = (d >> 4) & 15;
  int r2 = d & 15;
  int row = ((p >> 3) << 4) + r1;
  int col = ((p & 7) << 4) + r2;
  const float* src = e ? endp : init;
  size_t off = ((size_t)((b * PAIRS + pr) * NCH + c) << 14) + (size_t)row * HWP + col;
  A[i] = f2b(src[off]);
}

// ---------------- bf16 MFMA GEMM, 4-buffer DMA pipeline, ONE s_barrier/iter
// (R4 verified-best), BK=32 (R7 BK=64, R8 split-K, R11 zero-barrier-private
// all regressed). vmcnt(2*NC) before the barrier waits only the tile
// consumed now. BY-MAJOR XCD swizzle (R5): each XCD owns gy/8 contiguous
// row-bands -> A fetched once per chip, per-XCD set ~L2-resident.
// Tile BM(M) x NT(N), BK=32, 4 waves 2x2.
// MODE 0: outB = act(A·B^T + bias) bf16
// MODE 1: outB = raw partial, bf16 (R13: halves partial traffic; consumer
//         k_red_ln adds it into f32 residual, so bf16 suffices)
// MODE 2: pre epilogue: +bias+patch_pos+func_pos -> outF f32 + outB bf16
// MODE 3: post epilogue: +bias, depatchify scatter -> outF (A compact rows)
// GATHER: A rows are init-slot tokens of a full-layout buffer
template <int BM, int NT, int MODE, int GATHER>
__global__ __launch_bounds__(256) void k_mma(const u16* __restrict__ A,
                                             const u16* __restrict__ B,
                                             const float* __restrict__ bias,
                                             u16* __restrict__ outB,
                                             float* __restrict__ outF,
                                             const float* __restrict__ pp,
                                             const float* __restrict__ fp,
                                             int M, int N, int K, int act) {
  constexpr int FJ = NT / 32;                  // N-frags per wave
  constexpr int MI = BM / 32;                  // M-frags per wave
  constexpr int ACH = BM / 16;                 // A DMA chunks (16 rows each)
  constexpr int NC = (BM / 16 + NT / 16) / 4;  // DMA instrs per wave per stage
  __shared__ __align__(16) bf16_t As[4][BM][32];
  __shared__ __align__(16) bf16_t Bs[4][NT][32];
  const int t = threadIdx.x;
  const int w = t >> 6, lane = t & 63, quad = lane >> 4, l16 = lane & 15;
  int bx = blockIdx.x, by = blockIdx.y;
  if ((gridDim.y & 7) == 0) {       // by-major XCD swizzle (A-row locality)
    int lin = bx + gridDim.x * by;
    int xcd = lin & 7, slot = lin >> 3;
    int gx = gridDim.x;
    by = (gridDim.y >> 3) * xcd + slot / gx;
    bx = slot % gx;
  }
  const int row0 = by * BM, col0 = bx * NT;
  const int mB = (w & 1) * (BM / 2);
  const int nB = (w >> 1) * (NT / 2);

  // per-lane A-chunk source pointers
  const u16* aP[ACH];
#pragma unroll
  for (int c = 0; c < ACH; ++c) {
    int r = row0 + c * 16 + (lane >> 2);
    int g = r;
    if (GATHER) {
      int p = r & 63, pr = (r >> 6) % PAIRS, b = r / (PAIRS * PP);
      g = b * SEQ + pr * 128 + p;
    }
    aP[c] = A + (size_t)g * K + ((lane & 3) << 3);
  }
  const u16* bP = B + (size_t)(col0 + (lane >> 2)) * K + ((lane & 3) << 3);

  f32x4 acc[MI][FJ];
#pragma unroll
  for (int i = 0; i < MI; ++i)
#pragma unroll
    for (int j = 0; j < FJ; ++j) acc[i][j] = (f32x4){0.f, 0.f, 0.f, 0.f};

  auto stage = [&](int bu, int kk) {
#pragma unroll
    for (int s = 0; s < NC; ++s) {
      int c = NC * w + s;
      if (c < ACH) dma16(aP[c] + kk, &As[bu][c * 16][0]);
      else dma16(bP + (size_t)((c - ACH) * 16) * K + kk, &Bs[bu][(c - ACH) * 16][0]);
    }
  };

  const int iters = K >> 5;
  stage(0, 0);
  stage(1, 32);
  for (int it = 0; it < iters; ++it) {
    const int cur = it & 3;
    if (it + 2 < iters) stage((it + 2) & 3, (it + 2) << 5);  // stays in flight
    if (it + 2 < iters) vwait<2 * NC>();
    else if (it + 1 < iters) vwait<NC>();
    else vwait<0>();
    asm volatile("s_barrier" ::: "memory");   // single barrier: cur DMAs landed
    bf16x8 af[MI], bfr[FJ];
#pragma unroll
    for (int i = 0; i < MI; ++i)
      af[i] = *(const bf16x8*)&As[cur][mB + i * 16 + l16][quad * 8];
#pragma unroll
    for (int j = 0; j < FJ; ++j)
      bfr[j] = *(const bf16x8*)&Bs[cur][nB + j * 16 + l16][quad * 8];
#pragma unroll
    for (int i = 0; i < MI; ++i)
#pragma unroll
      for (int j = 0; j < FJ; ++j) acc[i][j] = MFMA16(af[i], bfr[j], acc[i][j]);
  }

#pragma unroll
  for (int i = 0; i < MI; ++i)
#pragma unroll
    for (int reg = 0; reg < 4; ++reg) {
      int m = row0 + mB + i * 16 + quad * 4 + reg;
#pragma unroll
      for (int j = 0; j < FJ; ++j) {
        int n = col0 + nB + j * 16 + l16;
        float v = acc[i][j][reg];
        if (MODE == 0) {
          v += bias[n];
          if (act) v = gelu_t(v);
          outB[(size_t)m * N + n] = f2b(v);
        } else if (MODE == 1) {
          outB[(size_t)m * N + n] = f2b(v);   // bf16 partial
        } else if (MODE == 2) {
          int p = m & 63, fi = (m >> 6) % FIN;
          v += bias[n] + pp[p * DIM + n] + fp[fi * DIM + n];
          outF[(size_t)m * N + n] = v;
          outB[(size_t)m * N + n] = f2b(v);
        } else {   // MODE 3: depatchify scatter (A/m compact init rows)
          v += bias[n];
          int p = m & 63, pr = (m >> 6) % PAIRS, b = m / (PAIRS * PP);
          int c = n >> 8, r1 = (n >> 4) & 15, r2 = n & 15;
          int row = ((p >> 3) << 4) + r1, col = ((p & 7) << 4) + r2;
          size_t off = ((size_t)((b * PAIRS + pr) * NCH + c) << 14) +
                       (size_t)row * HWP + col;
          outF[off] = v;
        }
      }
    }
}

// ---------------- fused flash attention (bf16 MFMA), ONE barrier per K-tile.
// R10 barrier audit: Ps and Qs are WAVE-LOCAL (rows [16w,16w+16) written and
// read by wave w only) -> softmax->PV sync and Q-stage sync unnecessary.
// K/V double-buffered: store tile kt+1 into parity buffer cur^1 (R4-style
// safety). LPT dispatch (R9): qblk reversed so heaviest blocks launch first.
// qmul: q-block stride (layer 5 only needs even q-blocks -> qmul=2)
__global__ __launch_bounds__(256) void k_attn(const u16* __restrict__ qkv,
                                              u16* __restrict__ o, int qmul) {
  __shared__ bf16_t Ks[2][64][72];
  __shared__ bf16_t Vs[2][64][72];   // transposed: Vs[.][d][tok]
  __shared__ bf16_t QPs[64][72];     // Q staging, then P transpose (wave-local)
  const int t = threadIdx.x;
  const int w = t >> 6, lane = t & 63, quad = lane >> 4, l16 = lane & 15;
  const int qblk = ((int)gridDim.x - 1 - (int)blockIdx.x) * qmul;  // LPT order
  const int h = blockIdx.y, b = blockIdx.z;
  const int q0 = qblk << 6;
  const u16* base = qkv + (size_t)b * SEQ * (3 * DIM);
  const int sr = t >> 2;
  const int sd = (t & 3) << 4;
  const int rowB = 3 * DIM;
  const int ntile = qblk + 1;
  // Q stage (wave-local rows)
  {
    const u16* qp = base + (size_t)(q0 + sr) * rowB + h * DHEAD + sd;
    *(bf16x8*)&QPs[sr][sd] = *(const bf16x8*)(const void*)qp;
    *(bf16x8*)&QPs[sr][sd + 8] = *(const bf16x8*)(const void*)(qp + 8);
  }
  // K/V tile 0 -> regs -> LDS buffer 0 (pre-loop)
  const u16* kp0 = base + (size_t)sr * rowB + DIM + h * DHEAD + sd;
  const u16* vp0 = base + (size_t)sr * rowB + 2 * DIM + h * DHEAD + sd;
  bf16x8 kR0 = *(const bf16x8*)(const void*)kp0;
  bf16x8 kR1 = *(const bf16x8*)(const void*)(kp0 + 8);
  bf16x8 vR0 = *(const bf16x8*)(const void*)vp0;
  bf16x8 vR1 = *(const bf16x8*)(const void*)(vp0 + 8);
  *(bf16x8*)&Ks[0][sr][sd] = kR0;
  *(bf16x8*)&Ks[0][sr][sd + 8] = kR1;
#pragma unroll
  for (int e = 0; e < 8; ++e) Vs[0][sd + e][sr] = vR0[e];
#pragma unroll
  for (int e = 0; e < 8; ++e) Vs[0][sd + 8 + e][sr] = vR1[e];
  __syncthreads();   // S0: Q + KV[0] visible
  bf16x8 aQ0 = *(const bf16x8*)&QPs[w * 16 + l16][quad * 8];
  bf16x8 aQ1 = *(const bf16x8*)&QPs[w * 16 + l16][32 + quad * 8];
  f32x4 accO[4];
#pragma unroll
  for (int j = 0; j < 4; ++j) accO[j] = (f32x4){0.f, 0.f, 0.f, 0.f};
  float mSt[4] = {-1e30f, -1e30f, -1e30f, -1e30f};
  float lSt[4] = {0.f, 0.f, 0.f, 0.f};
  for (int kt = 0; kt < ntile; ++kt) {
    const int cur = kt & 1;
    if (kt > 0) __syncthreads();   // single barrier: KV[cur] stores visible,
                                   // prior readers of KV[cur^1] done
    if (kt + 1 < ntile) {   // issue next-tile loads (consumed at end of iter)
      const u16* kp = kp0 + (size_t)(kt + 1) * 64 * rowB;
      const u16* vp = vp0 + (size_t)(kt + 1) * 64 * rowB;
      kR0 = *(const bf16x8*)(const void*)kp;
      kR1 = *(const bf16x8*)(const void*)(kp + 8);
      vR0 = *(const bf16x8*)(const void*)vp;
      vR1 = *(const bf16x8*)(const void*)(vp + 8);
    }
    f32x4 s[4];
#pragma unroll
    for (int j = 0; j < 4; ++j) {
      bf16x8 b0 = *(const bf16x8*)&Ks[cur][j * 16 + l16][quad * 8];
      bf16x8 b1 = *(const bf16x8*)&Ks[cur][j * 16 + l16][32 + quad * 8];
      s[j] = (f32x4){0.f, 0.f, 0.f, 0.f};
      s[j] = MFMA16(aQ0, b0, s[j]);
      s[j] = MFMA16(aQ1, b1, s[j]);
      s[j] *= 0.125f;
    }
#pragma unroll
    for (int reg = 0; reg < 4; ++reg) {
      float mx = fmaxf(fmaxf(s[0][reg], s[1][reg]), fmaxf(s[2][reg], s[3][reg]));
      mx = fmaxf(mx, __shfl_xor(mx, 1));
      mx = fmaxf(mx, __shfl_xor(mx, 2));
      mx = fmaxf(mx, __shfl_xor(mx, 4));
      mx = fmaxf(mx, __shfl_xor(mx, 8));
      float mNew = fmaxf(mSt[reg], mx);
      float alpha = __expf(mSt[reg] - mNew);
      mSt[reg] = mNew;
      float rs = 0.f;
#pragma unroll
      for (int j = 0; j < 4; ++j) {
        float p = __expf(s[j][reg] - mNew);
        s[j][reg] = p;
        rs += p;
      }
      rs += __shfl_xor(rs, 1);
      rs += __shfl_xor(rs, 2);
      rs += __shfl_xor(rs, 4);
      rs += __shfl_xor(rs, 8);
      lSt[reg] = lSt[reg] * alpha + rs;
#pragma unroll
      for (int j = 0; j < 4; ++j) accO[j][reg] *= alpha;
    }
    // P transpose via wave-local LDS rows (no barrier needed)
#pragma unroll
    for (int j = 0; j < 4; ++j)
#pragma unroll
      for (int reg = 0; reg < 4; ++reg)
        *(u16*)&QPs[w * 16 + quad * 4 + reg][j * 16 + l16] = f2b(s[j][reg]);
    // store next K/V tile into the other parity buffer (covers load latency
    // with the QK^T+softmax above; visibility at next iteration's barrier)
    if (kt + 1 < ntile) {
      const int nxt = cur ^ 1;
      *(bf16x8*)&Ks[nxt][sr][sd] = kR0;
      *(bf16x8*)&Ks[nxt][sr][sd + 8] = kR1;
#pragma unroll
      for (int e = 0; e < 8; ++e) Vs[nxt][sd + e][sr] = vR0[e];
#pragma unroll
      for (int e = 0; e < 8; ++e) Vs[nxt][sd + 8 + e][sr] = vR1[e];
    }
    bf16x8 aP0 = *(const bf16x8*)&QPs[w * 16 + l16][quad * 8];
    bf16x8 aP1 = *(const bf16x8*)&QPs[w * 16 + l16][32 + quad * 8];
#pragma unroll
    for (int jd = 0; jd < 4; ++jd) {
      bf16x8 b0 = *(const bf16x8*)&Vs[cur][jd * 16 + l16][quad * 8];
      bf16x8 b1 = *(const bf16x8*)&Vs[cur][jd * 16 + l16][32 + quad * 8];
      accO[jd] = MFMA16(aP0, b0, accO[jd]);
      accO[jd] = MFMA16(aP1, b1, accO[jd]);
    }
  }
#pragma unroll
  for (int reg = 0; reg < 4; ++reg) {
    float inv = 1.0f / lSt[reg];
    int row = q0 + w * 16 + quad * 4 + reg;
#pragma unroll
    for (int jd = 0; jd < 4; ++jd)
      o[((size_t)(b * SEQ + row)) * DIM + h * DHEAD + jd * 16 + l16] =
          f2b(accO[jd][reg] * inv);
  }
}

// ---------------- reduce + bias + residual + LayerNorm, WAVE-PER-ROW (R12):
// 4 rows/block, one row per wave; lane covers 8 cols (2x float4) -> 512 =
// 64 lanes x 8. Row reduction is a pure 6-step __shfl_xor over the wave —
// NO LDS, NO __syncthreads. R13: partial is bf16 (u16x8 load, exact b2f
// convert, f32 accumulate) — cuts this BW-saturated kernel's bytes ~14%.
// GIN: residual f_in is full-layout, gathered via init-slot map (layer-5 LN1).
template <int GIN>
__global__ __launch_bounds__(256) void k_red_ln(const u16* __restrict__ part,
                                                const float* __restrict__ bias,
                                                const float* __restrict__ f_in,
                                                float* __restrict__ f_out,
                                                u16* __restrict__ fb_out,
                                                const float* __restrict__ s,
                                                const float* __restrict__ bvec) {
  const int t = threadIdx.x;
  const int w = t >> 6, lane = t & 63;
  const int r = blockIdx.x * 4 + w;
  const int c = lane * 8;
  int g = r;
  if (GIN) {
    int p = r & 63, pr = (r >> 6) % PAIRS, b = r / (PAIRS * PP);
    g = b * SEQ + pr * 128 + p;
  }
  float4 x0 = *(const float4*)(f_in + (size_t)g * DIM + c);
  float4 x1 = *(const float4*)(f_in + (size_t)g * DIM + c + 4);
  u16x8 pb = *(const u16x8*)(part + (size_t)r * DIM + c);
  float4 b0 = *(const float4*)(bias + c);
  float4 b1 = *(const float4*)(bias + c + 4);
  x0.x += b2f(pb[0]) + b0.x; x0.y += b2f(pb[1]) + b0.y;
  x0.z += b2f(pb[2]) + b0.z; x0.w += b2f(pb[3]) + b0.w;
  x1.x += b2f(pb[4]) + b1.x; x1.y += b2f(pb[5]) + b1.y;
  x1.z += b2f(pb[6]) + b1.z; x1.w += b2f(pb[7]) + b1.w;
  float sum = x0.x + x0.y + x0.z + x0.w + x1.x + x1.y + x1.z + x1.w;
  float sq = x0.x * x0.x + x0.y * x0.y + x0.z * x0.z + x0.w * x0.w +
             x1.x * x1.x + x1.y * x1.y + x1.z * x1.z + x1.w * x1.w;
#pragma unroll
  for (int off = 32; off; off >>= 1) {
    sum += __shfl_xor(sum, off);
    sq += __shfl_xor(sq, off);
  }
  float mu = sum * (1.0f / 512.0f);
  float var = sq * (1.0f / 512.0f) - mu * mu;
  float rstd = rsqrtf(var + 1e-5f);
  float4 s0 = *(const float4*)(s + c);
  float4 s1 = *(const float4*)(s + c + 4);
  float4 v0 = *(const float4*)(bvec + c);
  float4 v1 = *(const float4*)(bvec + c + 4);
  float4 o0, o1;
  o0.x = (x0.x - mu) * rstd * s0.x + v0.x;
  o0.y = (x0.y - mu) * rstd * s0.y + v0.y;
  o0.z = (x0.z - mu) * rstd * s0.z + v0.z;
  o0.w = (x0.w - mu) * rstd * s0.w + v0.w;
  o1.x = (x1.x - mu) * rstd * s1.x + v1.x;
  o1.y = (x1.y - mu) * rstd * s1.y + v1.y;
  o1.z = (x1.z - mu) * rstd * s1.z + v1.z;
  o1.w = (x1.w - mu) * rstd * s1.w + v1.w;
  *(float4*)(f_out + (size_t)r * DIM + c) = o0;
  *(float4*)(f_out + (size_t)r * DIM + c + 4) = o1;
  u16x8 ob;
  ob[0] = f2b(o0.x); ob[1] = f2b(o0.y); ob[2] = f2b(o0.z); ob[3] = f2b(o0.w);
  ob[4] = f2b(o1.x); ob[5] = f2b(o1.y); ob[6] = f2b(o1.z); ob[7] = f2b(o1.w);
  *(u16x8*)(fb_out + (size_t)r * DIM + c) = ob;
}

extern "C" void kernel_launch(void* const* d_in, const int* in_sizes, int n_in,
                              void* d_out, int out_size, void* d_ws, size_t ws_size,
                              hipStream_t stream) {
  const float* init = (const float*)d_in[0];
  const float* endp = (const float*)d_in[1];
  const float* pre_W = (const float*)d_in[3];
  const float* pre_b = (const float*)d_in[4];
  const float* post_W = (const float*)d_in[5];
  const float* post_b = (const float*)d_in[6];
  const float* patch_pos = (const float*)d_in[7];
  const float* func_pos = (const float*)d_in[8];
  const float* Wqkv = (const float*)d_in[9];
  const float* bqkv = (const float*)d_in[10];
  const float* Wo = (const float*)d_in[11];
  const float* bo = (const float*)d_in[12];
  const float* ln1_s = (const float*)d_in[13];
  const float* ln1_b = (const float*)d_in[14];
  const float* ln2_s = (const float*)d_in[15];
  const float* ln2_b = (const float*)d_in[16];
  const float* W1 = (const float*)d_in[17];
  const float* b1 = (const float*)d_in[18];
  const float* W2 = (const float*)d_in[19];
  const float* b2 = (const float*)d_in[20];
  float* out = (float*)d_out;

  // ws layout (~105 MB; ws is 256 MB)
  char* p = (char*)d_ws;
  float* buf_f = (float*)p;    p += (size_t)NTOK * DIM * 4;    // f32 residual master
  u16* buf_fb = (u16*)p;       p += (size_t)NTOK * DIM * 2;    // bf16 stream
  u16* buf_attn = (u16*)p;     p += (size_t)NTOK * DIM * 2;
  u16* shared_b = (u16*)p;     p += (size_t)NTOK * DFF * 2;    // patch/qkv/hid alias
  u16* wAll = (u16*)p;         p += (size_t)N_CVT * 2;         // ALL weights bf16
  u16* partial = (u16*)p;      p += (size_t)NTOK * DIM * 2;    // bf16 partial (R13)
  float* buf_fc = (float*)p;   p += (size_t)MPOST * DIM * 4;   // layer-5 compact f32
  u16* buf_fbc = (u16*)p;      p += (size_t)MPOST * DIM * 2;   // layer-5 compact bf16
  u16* buf_patch = shared_b;
  u16* buf_qkv = shared_b;
  u16* buf_hid = shared_b;
  u16* wPre = wAll;
  u16* wPost = wAll + DIM * DIM;
  u16* wL = wAll + PREPOST;

  dim3 blk(256);
  const int elems = NTOK * DIM;

  k_cvt_all<<<N_CVT / (256 * 8), blk, 0, stream>>>(pre_W, post_W, Wqkv, Wo, W1, W2,
                                                   wAll);
  k_patchify<<<elems / 256, blk, 0, stream>>>(init, endp, buf_patch);
  // pre GEMM fused with bias+pos epilogue -> buf_f (f32) + buf_fb (bf16)
  k_mma<64, 64, 2, 0><<<dim3(8, 80), blk, 0, stream>>>(
      buf_patch, wPre, pre_b, buf_fb, buf_f, patch_pos, func_pos,
      NTOK, DIM, DIM, 0);

  for (int l = 0; l < NLAYER; ++l) {
    u16* wB = wL + (size_t)l * W_ALL;
    k_mma<64, 128, 0, 0><<<dim3(12, 80), blk, 0, stream>>>(
        buf_fb, wB, bqkv + (size_t)l * 3 * DIM, buf_qkv, nullptr, nullptr,
        nullptr, NTOK, 3 * DIM, DIM, 0);
    if (l < NLAYER - 1) {
      k_attn<<<dim3(SEQ / 64, NHEAD, BSZ), blk, 0, stream>>>(buf_qkv, buf_attn, 1);
      k_mma<64, 64, 1, 0><<<dim3(8, 80), blk, 0, stream>>>(
          buf_attn, wB + OFF_O, nullptr, partial, nullptr, nullptr, nullptr,
          NTOK, DIM, DIM, 0);
      k_red_ln<0><<<NTOK / 4, blk, 0, stream>>>(partial, bo + (size_t)l * DIM,
                                                buf_f, buf_f, buf_fb,
                                                ln1_s + (size_t)l * DIM,
                                                ln1_b + (size_t)l * DIM);
      k_mma<64, 128, 0, 0><<<dim3(16, 80), blk, 0, stream>>>(
          buf_fb, wB + OFF_1, b1 + (size_t)l * DFF, buf_hid, nullptr, nullptr,
          nullptr, NTOK, DFF, DIM, 1);
      k_mma<64, 64, 1, 0><<<dim3(8, 80), blk, 0, stream>>>(
          buf_hid, wB + OFF_2, nullptr, partial, nullptr, nullptr, nullptr,
          NTOK, DIM, DFF, 0);
      k_red_ln<0><<<NTOK / 4, blk, 0, stream>>>(partial, b2 + (size_t)l * DIM,
                                                buf_f, buf_f, buf_fb,
                                                ln2_s + (size_t)l * DIM,
                                                ln2_b + (size_t)l * DIM);
    } else {
      // layer 5: only init-slot rows matter downstream (exact trim)
      k_attn<<<dim3(SEQ / 128, NHEAD, BSZ), blk, 0, stream>>>(buf_qkv, buf_attn, 2);
      k_mma<64, 64, 1, 1><<<dim3(8, 40), blk, 0, stream>>>(     // proj, gathered A
          buf_attn, wB + OFF_O, nullptr, partial, nullptr, nullptr, nullptr,
          MPOST, DIM, DIM, 0);
      k_red_ln<1><<<MPOST / 4, blk, 0, stream>>>(partial, bo + (size_t)l * DIM,
                                                 buf_f, buf_fc, buf_fbc,
                                                 ln1_s + (size_t)l * DIM,
                                                 ln1_b + (size_t)l * DIM);
      k_mma<64, 128, 0, 0><<<dim3(16, 40), blk, 0, stream>>>(
          buf_fbc, wB + OFF_1, b1 + (size_t)l * DFF, buf_hid, nullptr, nullptr,
          nullptr, MPOST, DFF, DIM, 1);
      k_mma<64, 64, 1, 0><<<dim3(8, 40), blk, 0, stream>>>(
          buf_hid, wB + OFF_2, nullptr, partial, nullptr, nullptr, nullptr,
          MPOST, DIM, DFF, 0);
      k_red_ln<0><<<MPOST / 4, blk, 0, stream>>>(partial, b2 + (size_t)l * DIM,
                                                 buf_fc, buf_fc, buf_fbc,
                                                 ln2_s + (size_t)l * DIM,
                                                 ln2_b + (size_t)l * DIM);
    }
  }

  // post GEMM: compact A rows + bias + depatchify scatter (epilogue)
  k_mma<64, 64, 3, 0><<<dim3(8, 40), blk, 0, stream>>>(
      buf_fbc, wPost, post_b, nullptr, out, nullptr, nullptr,
      MPOST, DIM, DIM, 0);
}